// Round 4
// baseline (190.544 us; speedup 1.0000x reference)
//
#include <hip/hip_runtime.h>
#include <hip/hip_bf16.h>
#include <stdint.h>

#define BATCH 8192
#define GROWS 9216          // padded gather rows (>= 8192 + 7*127, rounded)
#define DIN   2048
#define DOUT  2048
#define NEXP  8
#define BM    128
#define BN    256
#define BK    32
#define NT    (DIN / BK)    // 64 K-tiles
#define NSLOT 72
#define BUFSZ 24576         // per K-tile buffer: A 8K + B 16K
#define BOFF  8192          // B region offset within buffer

typedef __attribute__((ext_vector_type(4))) float fx4;
typedef __attribute__((ext_vector_type(8))) short sx8;

__device__ __forceinline__ short f2b(float x){
  unsigned u = __float_as_uint(x);
  u = u + 0x7FFFu + ((u >> 16) & 1u);   // round-to-nearest-even
  return (short)(u >> 16);
}

__device__ __forceinline__ void gload16(const void* g, void* l){
  __builtin_amdgcn_global_load_lds(
      (const __attribute__((address_space(1))) unsigned int*)g,
      (__attribute__((address_space(3))) unsigned int*)l, 16, 0, 0);
}

// ---- bucket rows by expert into 128-aligned segments; slot->expert LUT; metadata tail ----
__global__ void prep_kernel(const int* __restrict__ actions, const int* __restrict__ mxs,
                            int* __restrict__ perm, int* __restrict__ meta,
                            float* __restrict__ out){
  __shared__ int cnt[NEXP], cur[NEXP];
  int t = threadIdx.x;
  for (int i = t; i < GROWS; i += 256) perm[i] = -1;
  if (t < NEXP) cnt[t] = 0;
  __syncthreads();
  for (int i = t; i < BATCH; i += 256){
    atomicAdd(&cnt[actions[i]], 1);
    out[(size_t)BATCH * DOUT + i]         = (float)mxs[i];
    out[(size_t)BATCH * DOUT + BATCH + i] = (float)actions[i];
  }
  __syncthreads();
  if (t == 0){
    int s = 0, slot = 0;
    for (int e = 0; e < NEXP; ++e){
      cur[e] = s;
      int ns = (cnt[e] + BM - 1) / BM;
      for (int q = 0; q < ns; ++q) meta[17 + slot++] = e;
      s += ns * BM;
    }
    meta[16] = slot;
  }
  __syncthreads();
  for (int i = t; i < BATCH; i += 256){
    int e = actions[i];
    perm[atomicAdd(&cur[e], 1)] = i;
  }
}

// ---- gather + convert: xp[i][k] = bf16(xs[perm[i]][k]); pad rows -> 0 ----
__global__ void gatherx_kernel(const float* __restrict__ xs, const int* __restrict__ perm,
                               short* __restrict__ xp){
  int i = blockIdx.x;
  int t = threadIdx.x;
  short v[8];
  int p = perm[i];
  if (p >= 0){
    const fx4* src = (const fx4*)(xs + (size_t)p * DIN + t * 8);
    fx4 a = src[0], b2 = src[1];
    v[0]=f2b(a.x); v[1]=f2b(a.y); v[2]=f2b(a.z); v[3]=f2b(a.w);
    v[4]=f2b(b2.x); v[5]=f2b(b2.y); v[6]=f2b(b2.z); v[7]=f2b(b2.w);
  } else {
#pragma unroll
    for (int j = 0; j < 8; ++j) v[j] = 0;
  }
  *(sx8*)(xp + (size_t)i * DIN + t * 8) = *(const sx8*)v;
}

// ---- W[e][k][n] f32 -> Wt[e][n][k] bf16 ----
__global__ void transw_kernel(const float* __restrict__ W, short* __restrict__ Wt){
  __shared__ float tile[64][69];
  int e  = blockIdx.z;
  int n0 = blockIdx.x * 64;
  int k0 = blockIdx.y * 64;
  const float* Wp = W + (size_t)e * DIN * DOUT + (size_t)k0 * DOUT + n0;
  int t = threadIdx.x;   // 256
#pragma unroll
  for (int it = 0; it < 4; ++it){
    int r = it * 16 + (t >> 4);
    int c = (t & 15) * 4;
    fx4 v = *(const fx4*)(Wp + (size_t)r * DOUT + c);
    tile[r][c] = v.x; tile[r][c+1] = v.y; tile[r][c+2] = v.z; tile[r][c+3] = v.w;
  }
  __syncthreads();
  int n  = t >> 2;
  int kc = (t & 3) * 16;
  short vv[16];
#pragma unroll
  for (int j = 0; j < 16; ++j) vv[j] = f2b(tile[kc + j][n]);
  short* dst = Wt + (size_t)e * DOUT * DIN + (size_t)(n0 + n) * DIN + k0 + kc;
  *(sx8*)dst       = *(const sx8*)vv;
  *(sx8*)(dst + 8) = *(const sx8*)(vv + 8);
}

// ---- grouped GEMM: 128x256xBK32, triple-buffer, 1 barrier + counted vmcnt per K-tile ----
__global__ __launch_bounds__(512, 4)
void moe_gemm_kernel(const short* __restrict__ xp, const short* __restrict__ Wt,
                     const float* __restrict__ bias, const int* __restrict__ perm,
                     const int* __restrict__ meta, float* __restrict__ out){
  __shared__ char lds[3 * BUFSZ];   // 72 KB -> 2 blocks/CU

  int F = blockIdx.x;               // 576 = 72 slots x 8 nb; XCD x ~ nb x
  int slot = F >> 3, nb = F & 7;
  int nslots = meta[16];
  if (slot >= nslots) return;
  int e      = meta[17 + slot];
  int m_base = slot * BM;           // global aligned row space
  int n0     = nb * BN;

  int t    = threadIdx.x;
  int wid  = t >> 6;
  int l    = t & 63;
  int wm   = wid & 1;               // 2 wave rows
  int wn   = wid >> 1;              // 4 wave cols
  int lrow = l & 15;
  int lk   = l >> 4;

  // ---- staging: LDS pos t*16 <-> (row, chunk) of row-pair-interleaved swizzled layout ----
  int srow = ((t >> 3) << 1) | ((t >> 2) & 1);
  int schk = (t & 3) ^ ((t >> 3) & 3);
  const char* ag  = (const char*)xp + ((size_t)(m_base + srow) * DIN + schk * 8) * 2;
  const char* bg0 = (const char*)Wt + (((size_t)e * DOUT + n0 + srow) * DIN + schk * 8) * 2;
  const char* bg1 = bg0 + (size_t)128 * DIN * 2;
  int ldst = t * 16;

#define STAGE(kt, BASE) do{ \
    gload16(ag  + (size_t)(kt) * 64, lds + (BASE) + ldst); \
    gload16(bg0 + (size_t)(kt) * 64, lds + (BASE) + BOFF + ldst); \
    gload16(bg1 + (size_t)(kt) * 64, lds + (BASE) + BOFF + 8192 + ldst); \
  }while(0)

  // ---- fragment read addresses (same involution as staging) ----
  int arow = wm * 64 + lrow;
  int aline = arow >> 1;
  int addrA = aline * 128 + (arow & 1) * 64 + ((lk ^ (aline & 3)) << 4);
  int brow = wn * 64 + lrow;
  int bline = brow >> 1;
  int addrB = BOFF + bline * 128 + (brow & 1) * 64 + ((lk ^ (bline & 3)) << 4);

  fx4 acc[4][4];
#pragma unroll
  for (int m = 0; m < 4; ++m)
#pragma unroll
    for (int n = 0; n < 4; ++n)
      acc[m][n] = (fx4){0.f, 0.f, 0.f, 0.f};

  float bcol[4];
#pragma unroll
  for (int n = 0; n < 4; ++n)
    bcol[n] = bias[(size_t)e * DOUT + n0 + wn * 64 + n * 16 + lrow];

#define KSTEP(CB, SB, DOSTG, kt) do{ \
    sx8 af[4], bf[4]; \
    _Pragma("unroll") for (int m = 0; m < 4; ++m) \
      af[m] = *(const sx8*)(lds + (CB) + addrA + m * 1024); \
    _Pragma("unroll") for (int n = 0; n < 4; ++n) \
      bf[n] = *(const sx8*)(lds + (CB) + addrB + n * 1024); \
    if (DOSTG) STAGE((kt) + 2, SB); \
    __builtin_amdgcn_s_setprio(1); \
    _Pragma("unroll") for (int m = 0; m < 4; ++m) \
    _Pragma("unroll") for (int n = 0; n < 4; ++n) \
      acc[m][n] = __builtin_amdgcn_mfma_f32_16x16x32_bf16(af[m], bf[n], acc[m][n], 0, 0, 0); \
    __builtin_amdgcn_s_setprio(0); \
    if (DOSTG) asm volatile("s_waitcnt vmcnt(3)" ::: "memory"); \
    else       asm volatile("s_waitcnt vmcnt(0)" ::: "memory"); \
    __builtin_amdgcn_s_barrier(); \
    asm volatile("" ::: "memory"); \
  }while(0)

  // ---- prologue: stage tiles 0,1 ----
  STAGE(0, 0);
  STAGE(1, BUFSZ);
  asm volatile("s_waitcnt vmcnt(3)" ::: "memory");   // tile 0 landed (all waves)
  __builtin_amdgcn_s_barrier();
  asm volatile("" ::: "memory");

  // ---- main loop: 64 K-tiles; buffer of tile t = (t%3)*BUFSZ ----
  for (int kt = 0; kt < 60; kt += 3){
    KSTEP(0,         2*BUFSZ, 1, kt);
    KSTEP(BUFSZ,     0,       1, kt + 1);
    KSTEP(2*BUFSZ,   BUFSZ,   1, kt + 2);
  }
  KSTEP(0,       2*BUFSZ, 1, 60);   // stages 62 -> buf2
  KSTEP(BUFSZ,   0,       1, 61);   // stages 63 -> buf0
  KSTEP(2*BUFSZ, 0,       0, 62);   // vmcnt(0): tile 63 landed
  KSTEP(0,       0,       0, 63);

  // ---- epilogue: scatter rows via perm, add bias ----
#pragma unroll
  for (int m = 0; m < 4; ++m){
    int rb = wm * 64 + m * 16 + lk * 4;
    int prow[4];
#pragma unroll
    for (int q = 0; q < 4; ++q)
      prow[q] = perm[m_base + rb + q];
#pragma unroll
    for (int n = 0; n < 4; ++n){
      int col = n0 + wn * 64 + n * 16 + lrow;
      fx4 v = acc[m][n];
#pragma unroll
      for (int q = 0; q < 4; ++q)
        if (prow[q] >= 0)
          out[(size_t)prow[q] * DOUT + col] = v[q] + bcol[n];
    }
  }
#undef KSTEP
#undef STAGE
}

extern "C" void kernel_launch(void* const* d_in, const int* in_sizes, int n_in,
                              void* d_out, int out_size, void* d_ws, size_t ws_size,
                              hipStream_t stream) {
  const float* xs      = (const float*)d_in[0];
  const float* W       = (const float*)d_in[1];
  const float* b       = (const float*)d_in[2];
  const int*   mxs     = (const int*)d_in[3];
  const int*   actions = (const int*)d_in[4];
  float* out = (float*)d_out;

  int*   perm = (int*)d_ws;                                   // GROWS ints
  int*   meta = (int*)((char*)d_ws + 40960);                  // [16]=nslots, [17+s]=expert
  short* Wt   = (short*)((char*)d_ws + 65536);                // 64 MB bf16 W^T
  short* xp   = (short*)((char*)d_ws + 65536 + (size_t)NEXP * DIN * DOUT * 2); // 37.75 MB

  hipLaunchKernelGGL(prep_kernel, dim3(1), dim3(256), 0, stream, actions, mxs, perm, meta, out);
  hipLaunchKernelGGL(gatherx_kernel, dim3(GROWS), dim3(256), 0, stream, xs, perm, xp);
  hipLaunchKernelGGL(transw_kernel, dim3(DOUT/64, DIN/64, NEXP), dim3(256), 0, stream, W, Wt);
  hipLaunchKernelGGL(moe_gemm_kernel, dim3(NSLOT * 8), dim3(512), 0, stream,
                     xp, Wt, b, perm, meta, out);
}